// Round 1
// baseline (222.626 us; speedup 1.0000x reference)
//
#include <hip/hip_runtime.h>
#include <math.h>

#define N_ROWS 65536
#define K_CODES 1024
#define C_DIM 64
#define KSPLIT 4
#define KPER (K_CODES / KSPLIT)   // 256 codes per split
#define CHUNK 128                 // codes staged in LDS per phase (32 KB)
#define BLK 256

// d_out layout (float32 elements), outputs concatenated in return order:
// [loss(1)][quantized_st(N*C)][perplexity(1)][indices(N)][avg_probs(K)]
#define OUT_LOSS 0
#define OUT_Q 1
#define OUT_PPL (1 + N_ROWS * C_DIM)     // 4194305
#define OUT_IDX (OUT_PPL + 1)            // 4194306
#define OUT_AVG (OUT_IDX + N_ROWS)       // 4259842

// d_ws layout (4-byte units)
#define WS_HIST 0                          // uint[K]
#define WS_EE 1024                         // float[K]
#define WS_LOSSP 2048                      // float[256] per-block loss partials
#define WS_PSCORE 2304                     // float[KSPLIT*N]
#define WS_PIDX (WS_PSCORE + KSPLIT * N_ROWS)  // int[KSPLIT*N]

// Kernel A: zero histogram, precompute ||e_k||^2
__global__ void vq_prep(const float* __restrict__ emb,
                        float* __restrict__ ee,
                        unsigned* __restrict__ hist) {
    int k = blockIdx.x * blockDim.x + threadIdx.x;
    if (k < K_CODES) {
        hist[k] = 0u;
        const float4* ev = (const float4*)(emb + (size_t)k * C_DIM);
        float s0 = 0.f, s1 = 0.f, s2 = 0.f, s3 = 0.f;
#pragma unroll
        for (int i = 0; i < 16; ++i) {
            float4 e = ev[i];
            s0 = fmaf(e.x, e.x, s0);
            s1 = fmaf(e.y, e.y, s1);
            s2 = fmaf(e.z, e.z, s2);
            s3 = fmaf(e.w, e.w, s3);
        }
        ee[k] = (s0 + s1) + (s2 + s3);
    }
}

// Kernel B: per-row partial argmin over a 256-code strip (blockIdx.y selects strip)
__global__ __launch_bounds__(BLK, 4) void vq_dist(
    const float* __restrict__ x, const float* __restrict__ emb,
    const float* __restrict__ ee,
    float* __restrict__ pscore, int* __restrict__ pidx) {
    __shared__ __align__(16) float sE[CHUNK * C_DIM];  // 32 KB
    __shared__ float sEE[CHUNK];

    const int row = blockIdx.x * BLK + threadIdx.x;
    const int k0 = blockIdx.y * KPER;

    // load this row's x into registers (64 floats)
    float xr[C_DIM];
    {
        const float4* xv = (const float4*)(x + (size_t)row * C_DIM);
#pragma unroll
        for (int i = 0; i < 16; ++i) {
            float4 v = xv[i];
            xr[4 * i + 0] = v.x;
            xr[4 * i + 1] = v.y;
            xr[4 * i + 2] = v.z;
            xr[4 * i + 3] = v.w;
        }
    }

    float best = 3.4028235e38f;
    int bidx = 0;

    for (int cs = 0; cs < KPER / CHUNK; ++cs) {
        const int kb = k0 + cs * CHUNK;
        __syncthreads();
        {
            const float4* src = (const float4*)(emb + (size_t)kb * C_DIM);
            float4* dst = (float4*)sE;
#pragma unroll
            for (int i = 0; i < (CHUNK * C_DIM / 4) / BLK; ++i)  // 8 float4 per thread
                dst[threadIdx.x + i * BLK] = src[threadIdx.x + i * BLK];
            if (threadIdx.x < CHUNK) sEE[threadIdx.x] = ee[kb + threadIdx.x];
        }
        __syncthreads();

#pragma unroll 2
        for (int kk = 0; kk < CHUNK; ++kk) {
            const float4* ev = (const float4*)(sE + kk * C_DIM);
            float d0 = 0.f, d1 = 0.f, d2 = 0.f, d3 = 0.f;
#pragma unroll
            for (int i = 0; i < 16; ++i) {
                float4 e = ev[i];
                d0 = fmaf(xr[4 * i + 0], e.x, d0);
                d1 = fmaf(xr[4 * i + 1], e.y, d1);
                d2 = fmaf(xr[4 * i + 2], e.z, d2);
                d3 = fmaf(xr[4 * i + 3], e.w, d3);
            }
            float dot = (d0 + d1) + (d2 + d3);
            float s = fmaf(-2.0f, dot, sEE[kk]);  // ||e||^2 - 2 x.e  (argmin-equivalent)
            if (s < best) { best = s; bidx = kb + kk; }  // strict < : first index wins
        }
    }

    pscore[(size_t)blockIdx.y * N_ROWS + row] = best;
    pidx[(size_t)blockIdx.y * N_ROWS + row] = bidx;
}

// Kernel C: combine splits -> final index; histogram; coalesced epilogue
// (quantized_st write + per-block loss partial)
__global__ __launch_bounds__(BLK) void vq_combine(
    const float* __restrict__ x, const float* __restrict__ emb,
    const float* __restrict__ pscore, const int* __restrict__ pidx,
    unsigned* __restrict__ hist, float* __restrict__ lossp,
    float* __restrict__ out) {
    __shared__ int sIdx[BLK];
    __shared__ unsigned sHist[K_CODES];
    __shared__ float sRed[BLK / 64];

    const int t = threadIdx.x;
    const int base = blockIdx.x * BLK;

    for (int i = t; i < K_CODES; i += BLK) sHist[i] = 0u;

    // combine partial argmins (ascending split order preserves first-index ties)
    const int row = base + t;
    float best = pscore[row];
    int bidx = pidx[row];
#pragma unroll
    for (int s = 1; s < KSPLIT; ++s) {
        float sc = pscore[(size_t)s * N_ROWS + row];
        int id = pidx[(size_t)s * N_ROWS + row];
        if (sc < best) { best = sc; bidx = id; }
    }
    sIdx[t] = bidx;
    out[OUT_IDX + row] = (float)bidx;
    __syncthreads();  // sHist zero + sIdx visible
    atomicAdd(&sHist[bidx], 1u);
    __syncthreads();
    for (int i = t; i < K_CODES; i += BLK) {
        unsigned c = sHist[i];
        if (c) atomicAdd(&hist[i], c);
    }

    // epilogue: 4 rows per iteration, lane-coalesced over columns
    float lsum = 0.f;
    const int rl0 = t >> 6;  // 0..3 (wave id)
    const int col = t & 63;
    for (int it = 0; it < BLK / 4; ++it) {
        const int rl = it * 4 + rl0;
        const int r = base + rl;
        const int bi = sIdx[rl];  // uniform within wave -> LDS broadcast
        float xv = x[(size_t)r * C_DIM + col];
        float qv = emb[(size_t)bi * C_DIM + col];
        float d = qv - xv;
        out[OUT_Q + (size_t)r * C_DIM + col] = xv + d;  // straight-through
        lsum = fmaf(d, d, lsum);
    }

    // deterministic block reduction of loss partial
#pragma unroll
    for (int o = 32; o > 0; o >>= 1) lsum += __shfl_down(lsum, o, 64);
    if ((t & 63) == 0) sRed[t >> 6] = lsum;
    __syncthreads();
    if (t == 0) lossp[blockIdx.x] = (sRed[0] + sRed[1]) + (sRed[2] + sRed[3]);
}

// Kernel D: avg_probs, perplexity, loss finalization
__global__ void vq_final(const unsigned* __restrict__ hist,
                         const float* __restrict__ lossp,
                         float* __restrict__ out) {
    __shared__ float sE[K_CODES];
    const int t = threadIdx.x;
    float p = (float)hist[t] * (1.0f / (float)N_ROWS);
    out[OUT_AVG + t] = p;
    sE[t] = p * logf(p + 1e-10f);
    __syncthreads();
    for (int o = 512; o > 0; o >>= 1) {
        if (t < o) sE[t] += sE[t + o];
        __syncthreads();
    }
    if (t == 0) {
        out[OUT_PPL] = expf(-sE[0]);
        float ls = 0.f;
        for (int i = 0; i < N_ROWS / BLK; ++i) ls += lossp[i];  // fixed order
        out[OUT_LOSS] = 0.25f * (ls / (float)(N_ROWS * C_DIM));
    }
}

extern "C" void kernel_launch(void* const* d_in, const int* in_sizes, int n_in,
                              void* d_out, int out_size, void* d_ws, size_t ws_size,
                              hipStream_t stream) {
    const float* x = (const float*)d_in[0];
    const float* emb = (const float*)d_in[1];
    float* out = (float*)d_out;
    float* ws_f = (float*)d_ws;
    unsigned* ws_u = (unsigned*)d_ws;
    int* ws_i = (int*)d_ws;

    vq_prep<<<K_CODES / BLK, BLK, 0, stream>>>(emb, ws_f + WS_EE, ws_u + WS_HIST);

    dim3 gB(N_ROWS / BLK, KSPLIT);
    vq_dist<<<gB, BLK, 0, stream>>>(x, emb, ws_f + WS_EE,
                                    ws_f + WS_PSCORE, ws_i + WS_PIDX);

    vq_combine<<<N_ROWS / BLK, BLK, 0, stream>>>(x, emb, ws_f + WS_PSCORE,
                                                 ws_i + WS_PIDX, ws_u + WS_HIST,
                                                 ws_f + WS_LOSSP, out);

    vq_final<<<1, K_CODES, 0, stream>>>(ws_u + WS_HIST, ws_f + WS_LOSSP, out);
}